// Round 1
// baseline (1169.088 us; speedup 1.0000x reference)
//
#include <hip/hip_runtime.h>

#define NB 4
#define NN 4096
#define NT 16
#define NC 64
#define NE 32768

// ---------------- tiny prep kernels ----------------

__global__ void k_zero(float* chan, int* count) {
  int i = blockIdx.x * blockDim.x + threadIdx.x;
  int stride = gridDim.x * blockDim.x;
  for (int idx = i; idx < NN; idx += stride) count[idx] = 0;
  for (int idx = i; idx < 128; idx += stride) chan[idx] = 0.f;
}

// Wt layout: float4 array, Wt4[(k*16+cq)*128 + o] = W[o, ci=4cq..4cq+3, k]
// WgT[c*64 + d] = Wg[d*64 + c]
__global__ void k_prep(const float* __restrict__ W1, const float* __restrict__ W2,
                       const float* __restrict__ Wg,
                       float* __restrict__ Wt1, float* __restrict__ Wt2,
                       float* __restrict__ WgT) {
  int i = blockIdx.x * blockDim.x + threadIdx.x;
  if (i < 24576) {
    int r = i & 3, o = (i >> 2) & 127, rowid = i >> 9;
    int k = rowid / 16, cq = rowid % 16, ci = cq * 4 + r;
    Wt1[i] = W1[o * 192 + ci * 3 + k];
    Wt2[i] = W2[o * 192 + ci * 3 + k];
  } else if (i < 24576 + 4096) {
    int j = i - 24576;
    int c = j >> 6, d = j & 63;
    WgT[j] = Wg[d * 64 + c];
  }
}

__global__ void k_count(const int* __restrict__ src, int* __restrict__ count) {
  int e = blockIdx.x * blockDim.x + threadIdx.x;
  if (e < NE) atomicAdd(&count[src[e]], 1);
}

__global__ void k_scan(const int* __restrict__ count, int* __restrict__ offsets,
                       int* __restrict__ cursor) {
  __shared__ int part[256];
  int tid = threadIdx.x;
  int base = tid * 16;
  int s = 0;
  for (int i = 0; i < 16; ++i) s += count[base + i];
  part[tid] = s;
  __syncthreads();
  if (tid == 0) {
    int r = 0;
    for (int i = 0; i < 256; ++i) { int t = part[i]; part[i] = r; r += t; }
    offsets[NN] = r;
  }
  __syncthreads();
  int r = part[tid];
  for (int i = 0; i < 16; ++i) {
    offsets[base + i] = r;
    cursor[base + i] = r;
    r += count[base + i];
  }
}

__global__ void k_place(const int* __restrict__ src, int* __restrict__ cursor,
                        int* __restrict__ esort) {
  int e = blockIdx.x * blockDim.x + threadIdx.x;
  if (e < NE) {
    int p = atomicAdd(&cursor[src[e]], 1);
    esort[p] = e;
  }
}

// ---------------- GLU1 + ReLU + GCN-linear, fused per (b,n) tile ----------------
// writes y in NODE-MAJOR layout: y[((n*NB + b)*NT + t)*NC + d]
__global__ __launch_bounds__(256) void k_glu1lin(
    const float* __restrict__ x, const float* __restrict__ Wt1,
    const float* __restrict__ b1, const float* __restrict__ WgT,
    const float* __restrict__ bg, float* __restrict__ y) {
  __shared__ float xs[18 * 64];   // conv-padded tile, rows 0 and 17 are zero
  __shared__ float hs[16 * 64];   // GLU output tile
  int tid = threadIdx.x;
  int bn = blockIdx.x;            // b*NN + n
  int n = bn & (NN - 1);
  int b = bn >> 12;

  // stage x tile (1024 floats) as float4
  {
    float4 v = ((const float4*)(x + (size_t)bn * 1024))[tid];
    int f = tid * 4, t = f >> 6, c = f & 63;
    *(float4*)&xs[(t + 1) * 64 + c] = v;
    if (tid < 32) {
      int row = (tid >> 4) ? 17 : 0;
      *(float4*)&xs[row * 64 + (tid & 15) * 4] = make_float4(0, 0, 0, 0);
    }
  }
  __syncthreads();

  int o = tid & 63, tg = tid >> 6;
  float av[4] = {0, 0, 0, 0}, ag[4] = {0, 0, 0, 0};
  const float4* Wt4 = (const float4*)Wt1;
  const float4* xs4 = (const float4*)xs;
  #pragma unroll
  for (int k = 0; k < 3; ++k)
    for (int cq = 0; cq < 16; ++cq) {
      float4 wv = Wt4[(k * 16 + cq) * 128 + o];
      float4 wg = Wt4[(k * 16 + cq) * 128 + o + 64];
      #pragma unroll
      for (int j = 0; j < 4; ++j) {
        float4 xv = xs4[(tg * 4 + j + k) * 16 + cq];
        av[j] += xv.x * wv.x + xv.y * wv.y + xv.z * wv.z + xv.w * wv.w;
        ag[j] += xv.x * wg.x + xv.y * wg.y + xv.z * wg.z + xv.w * wg.w;
      }
    }
  float bv = b1[o], bgate = b1[o + 64];
  #pragma unroll
  for (int j = 0; j < 4; ++j) {
    float v = av[j] + bv, g = ag[j] + bgate;
    float h = v / (1.f + __expf(-g));
    hs[(tg * 4 + j) * 64 + o] = fmaxf(h, 0.f);
  }
  __syncthreads();

  // linear: y[t][d] = bg[d] + sum_c hs[t][c] * Wg[d][c]
  int t = tid >> 4, dq = tid & 15;
  const float4* WgT4 = (const float4*)WgT;
  float4 acc = *(const float4*)&bg[dq * 4];
  for (int c = 0; c < 64; ++c) {
    float xv = hs[t * 64 + c];
    float4 w = WgT4[c * 16 + dq];
    acc.x += xv * w.x; acc.y += xv * w.y; acc.z += xv * w.z; acc.w += xv * w.w;
  }
  float4* ydst = (float4*)(y + ((size_t)n * NB + b) * 1024);
  ydst[t * 16 + dq] = acc;
}

// ---------------- GCN gather + ReLU + GLU2 + residual + stats, per node ----------------
__global__ __launch_bounds__(256) void k_gcnglu2(
    const float* __restrict__ y, const float* __restrict__ x,
    const float* __restrict__ Wt2, const float* __restrict__ b2,
    const int* __restrict__ offsets, const int* __restrict__ esort,
    const int* __restrict__ edge_dst, const float* __restrict__ ew,
    float* __restrict__ out, float* __restrict__ chan) {
  __shared__ float agg_s[4 * 18 * 64];  // per-b conv-padded tiles (18.4 KB)
  __shared__ float red[8 * 64];
  int tid = threadIdx.x;
  int n = blockIdx.x;
  int e0 = offsets[n], e1 = offsets[n + 1];

  float4 acc[4];
  #pragma unroll
  for (int q = 0; q < 4; ++q) acc[q] = make_float4(0, 0, 0, 0);
  for (int e = e0; e < e1; ++e) {
    int eid = esort[e];
    int dst = edge_dst[eid];
    float w = ew[eid];
    const float4* ysrc = (const float4*)(y + (size_t)dst * 4096);
    #pragma unroll
    for (int q = 0; q < 4; ++q) {
      float4 v = ysrc[tid + 256 * q];
      acc[q].x += w * v.x; acc[q].y += w * v.y;
      acc[q].z += w * v.z; acc[q].w += w * v.w;
    }
  }
  #pragma unroll
  for (int q = 0; q < 4; ++q) {
    int f = (tid + 256 * q) * 4;
    int b = f >> 10, t = (f >> 6) & 15, c = f & 63;
    float4 v;
    v.x = fmaxf(acc[q].x, 0.f); v.y = fmaxf(acc[q].y, 0.f);
    v.z = fmaxf(acc[q].z, 0.f); v.w = fmaxf(acc[q].w, 0.f);
    *(float4*)&agg_s[(b * 18 + t + 1) * 64 + c] = v;
  }
  if (tid < 128) {  // zero the conv pad rows
    int b = tid >> 5, row = ((tid >> 4) & 1) ? 17 : 0, c4 = tid & 15;
    *(float4*)&agg_s[(b * 18 + row) * 64 + c4 * 4] = make_float4(0, 0, 0, 0);
  }
  __syncthreads();

  int o = tid & 63, tg = tid >> 6;
  float bv = b2[o], bgate = b2[o + 64];
  const float4* Wt4 = (const float4*)Wt2;
  float ls1 = 0.f, ls2 = 0.f;
  for (int b = 0; b < 4; ++b) {
    const float4* as4 = (const float4*)&agg_s[b * 18 * 64];
    float av[4] = {0, 0, 0, 0}, ag[4] = {0, 0, 0, 0};
    #pragma unroll
    for (int k = 0; k < 3; ++k)
      for (int cq = 0; cq < 16; ++cq) {
        float4 wv = Wt4[(k * 16 + cq) * 128 + o];
        float4 wg = Wt4[(k * 16 + cq) * 128 + o + 64];
        #pragma unroll
        for (int j = 0; j < 4; ++j) {
          float4 xv = as4[(tg * 4 + j + k) * 16 + cq];
          av[j] += xv.x * wv.x + xv.y * wv.y + xv.z * wv.z + xv.w * wv.w;
          ag[j] += xv.x * wg.x + xv.y * wg.y + xv.z * wg.z + xv.w * wg.w;
        }
      }
    #pragma unroll
    for (int j = 0; j < 4; ++j) {
      int t = tg * 4 + j;
      float v = av[j] + bv, g = ag[j] + bgate;
      float h = v / (1.f + __expf(-g));
      size_t idx = (((size_t)b * NN + n) * 16 + t) * 64 + o;
      float res = h + x[idx];
      out[idx] = res;
      ls1 += res; ls2 += res * res;
    }
  }
  red[(tg * 2 + 0) * 64 + o] = ls1;
  red[(tg * 2 + 1) * 64 + o] = ls2;
  __syncthreads();
  if (tid < 64) {
    float s = red[0 * 64 + tid] + red[2 * 64 + tid] + red[4 * 64 + tid] + red[6 * 64 + tid];
    atomicAdd(&chan[tid], s);
  } else if (tid < 128) {
    int c = tid - 64;
    float s = red[1 * 64 + c] + red[3 * 64 + c] + red[5 * 64 + c] + red[7 * 64 + c];
    atomicAdd(&chan[64 + c], s);
  }
}

// ---------------- layernorm (global per-channel stats) + relu, in place ----------------
__global__ __launch_bounds__(256) void k_norm(
    float* __restrict__ out, const float* __restrict__ chan,
    const float* __restrict__ gamma, const float* __restrict__ beta) {
  __shared__ float sc[64], sh[64];
  int tid = threadIdx.x;
  if (tid < 64) {
    const float inv = 1.f / (float)(NB * NN * NT);
    float mean = chan[tid] * inv;
    float var = chan[64 + tid] * inv - mean * mean;
    float s = rsqrtf(var + 1e-5f) * gamma[tid];
    sc[tid] = s;
    sh[tid] = beta[tid] - mean * s;
  }
  __syncthreads();
  float4* o4 = (float4*)out;
  const int total = NB * NN * NT * 16;  // float4 count
  for (int i = blockIdx.x * blockDim.x + threadIdx.x; i < total;
       i += gridDim.x * blockDim.x) {
    float4 v = o4[i];
    int c = (i * 4) & 63;
    v.x = fmaxf(v.x * sc[c + 0] + sh[c + 0], 0.f);
    v.y = fmaxf(v.y * sc[c + 1] + sh[c + 1], 0.f);
    v.z = fmaxf(v.z * sc[c + 2] + sh[c + 2], 0.f);
    v.w = fmaxf(v.w * sc[c + 3] + sh[c + 3], 0.f);
    o4[i] = v;
  }
}

// ---------------- launch ----------------

extern "C" void kernel_launch(void* const* d_in, const int* in_sizes, int n_in,
                              void* d_out, int out_size, void* d_ws, size_t ws_size,
                              hipStream_t stream) {
  const float* x    = (const float*)d_in[0];
  const int* esrc   = (const int*)d_in[1];
  const int* edst   = (const int*)d_in[2];
  const float* ew   = (const float*)d_in[3];
  const float* W1   = (const float*)d_in[4];
  const float* b1   = (const float*)d_in[5];
  const float* Wg   = (const float*)d_in[6];
  const float* bg   = (const float*)d_in[7];
  const float* W2   = (const float*)d_in[8];
  const float* b2   = (const float*)d_in[9];
  const float* gamma = (const float*)d_in[10];
  const float* beta  = (const float*)d_in[11];
  float* out = (float*)d_out;

  float* ws = (float*)d_ws;
  float* y    = ws;                       // 16777216 floats (node-major)
  float* Wt1  = y + 16777216;             // 24576
  float* Wt2  = Wt1 + 24576;              // 24576
  float* WgT  = Wt2 + 24576;              // 4096
  float* chan = WgT + 4096;               // 128
  int* count   = (int*)(chan + 128);      // 4096
  int* offsets = count + 4096;            // 4097
  int* cursor  = offsets + 4097;          // 4096
  int* esort   = cursor + 4096;           // 32768

  hipLaunchKernelGGL(k_zero, dim3(32), dim3(256), 0, stream, chan, count);
  hipLaunchKernelGGL(k_prep, dim3(112), dim3(256), 0, stream, W1, W2, Wg, Wt1, Wt2, WgT);
  hipLaunchKernelGGL(k_count, dim3(128), dim3(256), 0, stream, esrc, count);
  hipLaunchKernelGGL(k_scan, dim3(1), dim3(256), 0, stream, count, offsets, cursor);
  hipLaunchKernelGGL(k_place, dim3(128), dim3(256), 0, stream, esrc, cursor, esort);
  hipLaunchKernelGGL(k_glu1lin, dim3(NB * NN), dim3(256), 0, stream,
                     x, Wt1, b1, WgT, bg, y);
  hipLaunchKernelGGL(k_gcnglu2, dim3(NN), dim3(256), 0, stream,
                     y, x, Wt2, b2, offsets, esort, edst, ew, out, chan);
  hipLaunchKernelGGL(k_norm, dim3(2048), dim3(256), 0, stream,
                     out, chan, gamma, beta);
}